// Round 1
// baseline (1496.032 us; speedup 1.0000x reference)
//
#include <hip/hip_runtime.h>

// LSTM: B=4096, T=60, F=128, H=256. x fp32 [B,T,F]; 4 gate weights [384,256] fp32.
// Strategy: per-block 32 batch rows, all 60 timesteps in one kernel (rows are
// independent across blocks -> no grid sync). bf16 MFMA 16x16x32 with fp32 acc.
// Weights packed gate-interleaved so each wave's 4 n-tiles are the 4 gates at the
// same j-block -> gate combine + c-state entirely in registers.

#define T_STEPS 60
#define F_DIM 128
#define H_DIM 256
#define K_DIM 384        // F + H
#define N_DIM 1024       // 4*H
#define BC 32            // batch rows per block
#define ZS 392           // zbuf row stride (384 + 8 pad bf16) -> 784 B, 16B-aligned, breaks bank conflicts
#define NBLOCKS 128      // 4096 / BC

typedef __attribute__((ext_vector_type(8))) short short8;
typedef __attribute__((ext_vector_type(4))) float floatx4;

__device__ __forceinline__ short f2bf(float f) {  // fp32 -> bf16 bits, RNE
    union { float f; unsigned u; } a; a.f = f;
    unsigned r = a.u + 0x7fffu + ((a.u >> 16) & 1u);
    return (short)(r >> 16);
}
__device__ __forceinline__ float bf2f(short b) {
    union { unsigned u; float f; } a; a.u = ((unsigned)(unsigned short)b) << 16;
    return a.f;
}
__device__ __forceinline__ float sigmoidf_(float x) {
    return 1.0f / (1.0f + __expf(-x));   // x<<0: expf->inf -> 0, safe
}
__device__ __forceinline__ float tanhf_(float x) {  // overflow-safe tanh
    float ax = fabsf(x);
    float e = __expf(-2.0f * ax);
    float t = (1.0f - e) / (1.0f + e);
    return copysignf(t, x);
}

// Pack gate weights into bf16 MFMA B-fragments.
// frag = nt*12 + ks, nt in [0,64): gate g = nt&3, jblk = nt>>2 (gate-interleaved).
// lane l, elem e -> W_g[k = ks*32 + (l>>4)*8 + e][jblk*16 + (l&15)].
__global__ void pack_w_kernel(const float* __restrict__ Wf, const float* __restrict__ Wu,
                              const float* __restrict__ Wc, const float* __restrict__ Wo,
                              short* __restrict__ wpack) {
    int gt = blockIdx.x * 256 + threadIdx.x;   // 768 frags * 64 lanes = 49152 threads
    int frag = gt >> 6;
    int lane = gt & 63;
    int nt = frag / 12;
    int ks = frag - nt * 12;
    int g = nt & 3;
    int jblk = nt >> 2;
    int k0 = ks * 32 + ((lane >> 4) << 3);
    int col = jblk * 16 + (lane & 15);
    const float* W = (g == 0) ? Wf : (g == 1) ? Wu : (g == 2) ? Wc : Wo;
    short8 v;
#pragma unroll
    for (int e = 0; e < 8; ++e)
        v[e] = f2bf(W[(size_t)(k0 + e) * H_DIM + col]);
    *(short8*)(wpack + (size_t)frag * 512 + lane * 8) = v;
}

// Head is linear: out[b] = h[b]·v + s, v[j] = sum_k Wd1[j][k]*Wd2[k], s = bd1·Wd2 + bd2.
__global__ void head_prep_kernel(const float* __restrict__ Wd1, const float* __restrict__ bd1,
                                 const float* __restrict__ Wd2, const float* __restrict__ bd2,
                                 float* __restrict__ vhead, float* __restrict__ shead) {
    int j = threadIdx.x;  // 256
    float s = 0.f;
    for (int k = 0; k < H_DIM; ++k)
        s += Wd1[(size_t)j * H_DIM + k] * Wd2[k];
    vhead[j] = s;
    if (j == 0) {
        float t = 0.f;
        for (int k = 0; k < H_DIM; ++k) t += bd1[k] * Wd2[k];
        shead[0] = t + bd2[0];
    }
}

__global__ __launch_bounds__(1024) void lstm_kernel(
        const float* __restrict__ x,
        const float* __restrict__ bfv, const float* __restrict__ buv,
        const float* __restrict__ bcv, const float* __restrict__ bov,
        const short* __restrict__ wpack,
        const float* __restrict__ vhead, const float* __restrict__ shead,
        float* __restrict__ out)
{
    // z = [x_t | h] as bf16, 32 rows x 392 (384 + pad)
    __shared__ __align__(16) short zbuf[BC * ZS];

    const int tid  = threadIdx.x;
    const int wave = tid >> 6;      // 16 waves
    const int lane = tid & 63;
    const int quad = lane >> 4;
    const int l15  = lane & 15;
    const int b0   = blockIdx.x * BC;

    // zero h region (and everything else; x region overwritten each step)
    for (int i = tid; i < BC * ZS; i += 1024) zbuf[i] = 0;

    // this lane's gate column j (same for all 4 acc tiles thanks to interleaved pack)
    const int j = wave * 16 + l15;
    const float bfr = bfv[j], bur = buv[j], bcr = bcv[j], bor = bov[j];

    floatx4 creg[2] = {};  // c state: cell (row = mt*16 + quad*4 + r, col j)

    // wave's fragment base: nt = wave*4 + g
    const short* wbase = wpack + (size_t)(wave * 48) * 512 + lane * 8;

    for (int t = 0; t < T_STEPS; ++t) {
        // ---- stage x_t: 32 rows x 128 fp32 -> bf16 in zbuf cols [0,128) ----
        {
            int r = tid >> 5;               // 0..31
            int f = (tid & 31) << 2;        // 0..124
            float4 xv = *(const float4*)(x + ((size_t)(b0 + r) * T_STEPS + t) * F_DIM + f);
            ushort4 h4;
            h4.x = (unsigned short)f2bf(xv.x);
            h4.y = (unsigned short)f2bf(xv.y);
            h4.z = (unsigned short)f2bf(xv.z);
            h4.w = (unsigned short)f2bf(xv.w);
            *(ushort4*)(&zbuf[r * ZS + f]) = h4;
        }
        __syncthreads();   // staging + prev-step h writes visible

        // ---- preacts: [32 x 384] @ [384 x 1024] (this wave: 64 cols = 4 gates @ jblk=wave) ----
        floatx4 acc[2][4] = {};
#pragma unroll
        for (int ks = 0; ks < 12; ++ks) {
            short8 a0 = *(const short8*)(&zbuf[l15 * ZS + ks * 32 + quad * 8]);
            short8 a1 = *(const short8*)(&zbuf[(16 + l15) * ZS + ks * 32 + quad * 8]);
#pragma unroll
            for (int g = 0; g < 4; ++g) {
                short8 b = *(const short8*)(wbase + (size_t)(g * 12 + ks) * 512);
                acc[0][g] = __builtin_amdgcn_mfma_f32_16x16x32_bf16(a0, b, acc[0][g], 0, 0, 0);
                acc[1][g] = __builtin_amdgcn_mfma_f32_16x16x32_bf16(a1, b, acc[1][g], 0, 0, 0);
            }
        }
        __syncthreads();   // all zbuf reads done before h overwrite

        // ---- gates + state update, all in registers; write h (bf16) to zbuf ----
#pragma unroll
        for (int mt = 0; mt < 2; ++mt) {
#pragma unroll
            for (int r = 0; r < 4; ++r) {
                float pf = acc[mt][0][r] + bfr;
                float pu = acc[mt][1][r] + bur;
                float pc = acc[mt][2][r] + bcr;
                float po = acc[mt][3][r] + bor;
                float fg = sigmoidf_(pf);
                float ug = sigmoidf_(pu);
                float gg = tanhf_(pc);
                float og = sigmoidf_(po);
                float cn = fg * creg[mt][r] + ug * gg;
                creg[mt][r] = cn;
                float hn = og * tanhf_(cn);
                int row = mt * 16 + quad * 4 + r;   // C/D layout: row = quad*4+reg
                zbuf[row * ZS + F_DIM + j] = f2bf(hn);
            }
        }
        // no trailing sync needed: next iter's stage touches disjoint cols,
        // and its __syncthreads() orders h-writes before the next MFMA reads.
    }
    __syncthreads();

    // ---- head: out[b] = h[b]·v + s ----
    {
        int r  = (wave << 1) + (lane >> 5);   // 0..31, half-wave per row
        int jl = (lane & 31) << 3;            // 8 elems per lane
        float sum = 0.f;
#pragma unroll
        for (int e = 0; e < 8; ++e)
            sum += bf2f(zbuf[r * ZS + F_DIM + jl + e]) * vhead[jl + e];
#pragma unroll
        for (int off = 16; off >= 1; off >>= 1)
            sum += __shfl_down(sum, off, 64);
        if ((lane & 31) == 0)
            out[b0 + r] = sum + shead[0];
    }
}

extern "C" void kernel_launch(void* const* d_in, const int* in_sizes, int n_in,
                              void* d_out, int out_size, void* d_ws, size_t ws_size,
                              hipStream_t stream) {
    (void)in_sizes; (void)n_in; (void)out_size; (void)ws_size;
    const float* x   = (const float*)d_in[0];
    const float* Wf  = (const float*)d_in[1];
    const float* bfv = (const float*)d_in[2];
    const float* Wu  = (const float*)d_in[3];
    const float* buv = (const float*)d_in[4];
    const float* Wc  = (const float*)d_in[5];
    const float* bcv = (const float*)d_in[6];
    const float* Wo  = (const float*)d_in[7];
    const float* bov = (const float*)d_in[8];
    const float* Wd1 = (const float*)d_in[9];
    const float* bd1 = (const float*)d_in[10];
    const float* Wd2 = (const float*)d_in[11];
    const float* bd2 = (const float*)d_in[12];

    short* wpack = (short*)d_ws;                                  // 384*1024*2 = 768 KB
    float* vhead = (float*)((char*)d_ws + (size_t)K_DIM * N_DIM * 2);
    float* shead = vhead + H_DIM;

    pack_w_kernel<<<192, 256, 0, stream>>>(Wf, Wu, Wc, Wo, wpack);
    head_prep_kernel<<<1, 256, 0, stream>>>(Wd1, bd1, Wd2, bd2, vhead, shead);
    lstm_kernel<<<NBLOCKS, 1024, 0, stream>>>(x, bfv, buv, bcv, bov, wpack, vhead, shead,
                                              (float*)d_out);
}